// Round 2
// baseline (673.980 us; speedup 1.0000x reference)
//
#include <hip/hip_runtime.h>

// DiffeomorphicTransform: flow = velocity/2^7; 7x { grid = sample_grid + flow*rf;
// flow = flow + trilerp(flow, grid) }  (border clamp, align_corners=True)
//
// R2: 4 voxels (consecutive x) per thread. float4 loads for flow/grid/store;
// 96 independent gather dwords in flight per thread (latency-bound fix).

constexpr int D = 128, H = 160, W = 128;
constexpr int N = D * H * W;          // 2,621,440 voxels (divisible by 4)
constexpr int NT = N / 4;             // threads per dispatch

__global__ __launch_bounds__(256)
void diffeo_step(const float* __restrict__ src,   // [3][N] flow (deferred scale)
                 const float* __restrict__ grid,  // [N][3]
                 const float* __restrict__ rf_p,  // scalar range_flow
                 float* __restrict__ dst,         // [3][N]
                 float scale)                     // 1/128 on step 1, else 1.0
{
    const int t = blockIdx.x * blockDim.x + threadIdx.x;  // [0, NT)
    const float rf = rf_p[0];
    const int i0 = 4 * t;                                 // first voxel

    // vectorized flow + grid loads (16 B/lane, fully coalesced)
    const float4 fx4 = ((const float4*)(src))[t];
    const float4 fy4 = ((const float4*)(src + N))[t];
    const float4 fz4 = ((const float4*)(src + 2 * N))[t];
    const float4 g0 = ((const float4*)grid)[3 * t + 0];
    const float4 g1 = ((const float4*)grid)[3 * t + 1];
    const float4 g2 = ((const float4*)grid)[3 * t + 2];

    const float fx[4] = {fx4.x, fx4.y, fx4.z, fx4.w};
    const float fy[4] = {fy4.x, fy4.y, fy4.z, fy4.w};
    const float fz[4] = {fz4.x, fz4.y, fz4.z, fz4.w};
    const float gx[4] = {g0.x, g0.w, g1.z, g2.y};
    const float gy[4] = {g0.y, g1.x, g1.w, g2.z};
    const float gz[4] = {g0.z, g1.y, g2.x, g2.w};

    float fs[3][4];        // scaled flow (the "base" term and store value part 1)
    float wgt[4][8];       // 8 trilinear weights per voxel
    int   ofs[4][8];       // 8 gather offsets per voxel (channel 0)

#pragma unroll
    for (int j = 0; j < 4; ++j) {
        const float fxs = fx[j] * scale;
        const float fys = fy[j] * scale;
        const float fzs = fz[j] * scale;
        fs[0][j] = fxs; fs[1][j] = fys; fs[2][j] = fzs;

        const float px = gx[j] + fxs * rf;
        const float py = gy[j] + fys * rf;
        const float pz = gz[j] + fzs * rf;

        const float ix = fminf(fmaxf((px + 1.0f) * 0.5f * (float)(W - 1), 0.0f), (float)(W - 1));
        const float iy = fminf(fmaxf((py + 1.0f) * 0.5f * (float)(H - 1), 0.0f), (float)(H - 1));
        const float iz = fminf(fmaxf((pz + 1.0f) * 0.5f * (float)(D - 1), 0.0f), (float)(D - 1));

        const float x0f = floorf(ix), y0f = floorf(iy), z0f = floorf(iz);
        const float wx = ix - x0f, wy = iy - y0f, wz = iz - z0f;
        const int x0 = (int)x0f, y0 = (int)y0f, z0 = (int)z0f;
        const int x1 = min(x0 + 1, W - 1);
        const int y1 = min(y0 + 1, H - 1);
        const int z1 = min(z0 + 1, D - 1);

        const int b00 = (z0 * H + y0) * W;
        const int b01 = (z0 * H + y1) * W;
        const int b10 = (z1 * H + y0) * W;
        const int b11 = (z1 * H + y1) * W;

        ofs[j][0] = b00 + x0; ofs[j][1] = b00 + x1;
        ofs[j][2] = b01 + x0; ofs[j][3] = b01 + x1;
        ofs[j][4] = b10 + x0; ofs[j][5] = b10 + x1;
        ofs[j][6] = b11 + x0; ofs[j][7] = b11 + x1;

        const float omx = 1.0f - wx, omy = 1.0f - wy, omz = 1.0f - wz;
        wgt[j][0] = omz * omy * omx; wgt[j][1] = omz * omy * wx;
        wgt[j][2] = omz * wy  * omx; wgt[j][3] = omz * wy  * wx;
        wgt[j][4] = wz  * omy * omx; wgt[j][5] = wz  * omy * wx;
        wgt[j][6] = wz  * wy  * omx; wgt[j][7] = wz  * wy  * wx;
    }

    // gathers: 3 channels x 4 voxels x 8 corners, all independent
    float out[3][4];
#pragma unroll
    for (int c = 0; c < 3; ++c) {
        const float* __restrict__ s = src + c * N;
#pragma unroll
        for (int j = 0; j < 4; ++j) {
            float v = wgt[j][0] * s[ofs[j][0]] + wgt[j][1] * s[ofs[j][1]]
                    + wgt[j][2] * s[ofs[j][2]] + wgt[j][3] * s[ofs[j][3]]
                    + wgt[j][4] * s[ofs[j][4]] + wgt[j][5] * s[ofs[j][5]]
                    + wgt[j][6] * s[ofs[j][6]] + wgt[j][7] * s[ofs[j][7]];
            out[c][j] = fs[c][j] + v * scale;   // deferred scale (trilerp is linear)
        }
    }

#pragma unroll
    for (int c = 0; c < 3; ++c)
        ((float4*)(dst + c * N))[t] = make_float4(out[c][0], out[c][1], out[c][2], out[c][3]);
    (void)i0;
}

extern "C" void kernel_launch(void* const* d_in, const int* in_sizes, int n_in,
                              void* d_out, int out_size, void* d_ws, size_t ws_size,
                              hipStream_t stream)
{
    const float* vel  = (const float*)d_in[0];   // [1,3,128,160,128]
    const float* grid = (const float*)d_in[1];   // [1,128,160,128,3]
    const float* rf   = (const float*)d_in[2];   // scalar
    float* out = (float*)d_out;                  // [1,3,128,160,128]
    float* ws  = (float*)d_ws;                   // needs 3*N*4 = 31.5 MB

    const dim3 blk(256);
    const dim3 grd(NT / 256);                    // 2560 blocks, exact

    // step 1: velocity (deferred /128) -> out
    diffeo_step<<<grd, blk, 0, stream>>>(vel, grid, rf, out, 1.0f / 128.0f);
    // steps 2..7 ping-pong: out->ws, ws->out, ... ; step 7 ends in d_out
    float* bufs[2] = {out, ws};
    for (int it = 2; it <= 7; ++it) {
        float* s = bufs[it & 1];
        float* d = bufs[(it + 1) & 1];
        diffeo_step<<<grd, blk, 0, stream>>>(s, grid, rf, d, 1.0f);
    }
}